// Round 1
// 189.624 us; speedup vs baseline: 1.0051x; 1.0051x over previous
//
#include <hip/hip_runtime.h>
#include <hip/hip_bf16.h>
#include <hip/hip_fp16.h>

// N=4096 nodes, E=4096 hyperedges, F=256, H=256. All float tensors f32;
// batch_mask int32. out = 8192 f32: [pos_score | neg_score].
//
// R1 structure: 4 kernels (was 5).
//   k_prep      : pack mask bitmap + transpose W to bf16
//   k_gemm_relu : MFMA GEMM, epilogue writes h TRANSPOSED (hT[c][r]) directly
//                 (transpose kernel eliminated; MFMA C-layout gives 4 contiguous
//                  rows per lane -> 8B ushort4 stores, same 32B segments)
//   k_sort      : per-column LSD radix sort in LDS; emits ONLY top-64/bot-64
//                 keys per column (8 MB sortedAsc write eliminated;
//                 P(need >64 probes) = 2^-64, exact scan fallback kept)
//   k_probe     : 8-wide batched probe vs LDS top/bot-16, global top/bot-64
//                 fallback, exact hT column scan as final correctness net.

typedef short bf16x8 __attribute__((ext_vector_type(8)));
typedef float f32x4 __attribute__((ext_vector_type(4)));
typedef short s16x2 __attribute__((ext_vector_type(2)));
typedef unsigned short u16x2 __attribute__((ext_vector_type(2)));

static __device__ __forceinline__ unsigned short f2bf(float f) {
    __hip_bfloat16 b = __float2bfloat16(f);
    return __builtin_bit_cast(unsigned short, b);
}
static __device__ __forceinline__ float f16u_to_f(unsigned u) {
    __half h = __builtin_bit_cast(__half, (unsigned short)(u & 0xffffu));
    return __half2float(h);
}
static __device__ __forceinline__ unsigned pkmax_i16(unsigned a, unsigned b) {
    s16x2 r = __builtin_elementwise_max(__builtin_bit_cast(s16x2, a), __builtin_bit_cast(s16x2, b));
    return __builtin_bit_cast(unsigned, r);
}
static __device__ __forceinline__ unsigned pkmin_u16(unsigned a, unsigned b) {
    u16x2 r = __builtin_elementwise_min(__builtin_bit_cast(u16x2, a), __builtin_bit_cast(u16x2, b));
    return __builtin_bit_cast(unsigned, r);
}

// ---------------------------------------------------------------- prep: W transpose + mask pack (fused)
// bx < 2048: pack mask word bx*256+t (NON-inverted, MSB-first:
//   bit (31-j) of packed[e][w] = mask[e][w*32+j];
//   membership test for idx: (int)(word << (idx&31)) < 0).
// bx >= 2048: Wt[n][k] = bf16(W[k][n]).
__global__ void k_prep(const int* __restrict__ mask, unsigned* __restrict__ packed,
                       const float* __restrict__ Ws, const float* __restrict__ Wh,
                       unsigned short* __restrict__ Wts, unsigned short* __restrict__ Wth) {
    const int bx = blockIdx.x, t = threadIdx.x;
    if (bx < 2048) {
        int w = bx * 256 + t;
        const int* p = mask + (size_t)w * 32;
        unsigned word = 0;
#pragma unroll
        for (int j = 0; j < 32; j += 4) {
            int4 m = *(const int4*)(p + j);
            word |= (m.x != 0 ? (1u << (31 - j)) : 0u)
                  | (m.y != 0 ? (1u << (30 - j)) : 0u)
                  | (m.z != 0 ? (1u << (29 - j)) : 0u)
                  | (m.w != 0 ? (1u << (28 - j)) : 0u);
        }
        packed[w] = word;
    } else {
        int b2 = bx - 2048;            // 0..511
        int k = b2 & 255, brn = b2 >> 8;
        const float* W     = brn ? Wh : Ws;
        unsigned short* Wt = brn ? Wth : Wts;
        Wt[t * 256 + k] = f2bf(W[k * 256 + t]);
    }
}

// ---------------------------------------------------------------- GEMM + relu -> f16 h
// tmode=1: write hOut TRANSPOSED as hT[br][c][r]  (main path; feeds k_sort)
// tmode=0: write hOut row-major   as h [br][r][c] (fallback path; feeds k_pool9)
__launch_bounds__(256)
__global__ void k_gemm_relu(const float* __restrict__ pXf, const float* __restrict__ pXm,
                            const float* __restrict__ nXf, const float* __restrict__ nXm,
                            const unsigned short* __restrict__ Wts, const unsigned short* __restrict__ Wth,
                            const float* __restrict__ bs,  const float* __restrict__ bh,
                            unsigned short* __restrict__ hOut, int tmode) {
    const int t  = threadIdx.x;
    const int wv = t >> 6;
    const int l  = t & 63;
    const int lm = l & 15;
    const int q  = l >> 4;
    const int bz = blockIdx.z;
    const float* Xf = bz ? nXf : pXf;
    const float* Xm = bz ? nXm : pXm;
    unsigned short* hb = hOut + (size_t)bz * 4096 * 256;

    const int m0 = blockIdx.x * 64 + wv * 16;
    const int n0 = blockIdx.y * 64;

    f32x4 acc[4] = {};
#pragma unroll
    for (int ks = 0; ks < 512; ks += 32) {
        const float* X           = (ks < 256) ? Xf : Xm;
        const unsigned short* Wt = (ks < 256) ? Wts : Wth;
        const int kk = (ks & 255) + q * 8;
        float4 a0 = *(const float4*)(X + (m0 + lm) * 256 + kk);
        float4 a1 = *(const float4*)(X + (m0 + lm) * 256 + kk + 4);
        bf16x8 a;
        a[0] = (short)f2bf(a0.x); a[1] = (short)f2bf(a0.y);
        a[2] = (short)f2bf(a0.z); a[3] = (short)f2bf(a0.w);
        a[4] = (short)f2bf(a1.x); a[5] = (short)f2bf(a1.y);
        a[6] = (short)f2bf(a1.z); a[7] = (short)f2bf(a1.w);
#pragma unroll
        for (int nt = 0; nt < 4; nt++) {
            bf16x8 b = *(const bf16x8*)(Wt + (n0 + nt * 16 + lm) * 256 + kk);
            acc[nt] = __builtin_amdgcn_mfma_f32_16x16x32_bf16(a, b, acc[nt], 0, 0, 0);
        }
    }
    if (tmode) {
        // C-fragment: col = n0+nt*16+lm, rows m0+q*4+i (i=0..3 contiguous).
        // hT[c][r]: 4 contiguous u16 per lane -> one 8B store; lanes q=0..3 of
        // the same column form a 32B contiguous segment.
#pragma unroll
        for (int nt = 0; nt < 4; nt++) {
            const int c = n0 + nt * 16 + lm;
            const float bsum = bs[c] + bh[c];
            ushort4 v4;
#pragma unroll
            for (int i = 0; i < 4; i++) {
                float v = acc[nt][i] + bsum;
                v = v > 0.f ? v : 0.f;   // relu => h >= +0.0 (u16-monotonic f16 bits)
                ((unsigned short*)&v4)[i] = __builtin_bit_cast(unsigned short, __float2half(v));
            }
            *(ushort4*)(hb + (size_t)c * 4096 + m0 + q * 4) = v4;
        }
    } else {
#pragma unroll
        for (int nt = 0; nt < 4; nt++) {
            const int c = n0 + nt * 16 + lm;
            const float bsum = bs[c] + bh[c];
#pragma unroll
            for (int i = 0; i < 4; i++) {
                const int r = m0 + q * 4 + i;
                float v = acc[nt][i] + bsum;
                v = v > 0.f ? v : 0.f;
                hb[(size_t)r * 256 + c] = __builtin_bit_cast(unsigned short, __float2half(v));
            }
        }
    }
}

// ---------------------------------------------------------------- per-column LSD radix sort
// One block per (col, branch). keys = (f16bits << 16) | idx; 4 passes x
// 4-bit digits over the value field. Per-thread histograms + flattened
// exclusive scan -> stable deterministic ranks, no atomics. Wave sums are
// parked in the scatter-destination buffer (free until 2 barriers later),
// keeping LDS at exactly 40 KB -> 4 blocks/CU. Emits only top-64/bot-64
// keys per column (full sorted array no longer materialized to global).
// grid (256, 2), block 256.
__launch_bounds__(256)
__global__ void k_sort(const unsigned short* __restrict__ hT,
                       unsigned* __restrict__ topkG, unsigned* __restrict__ botkG) {
    __shared__ unsigned arrA[4096];              // 16 KB
    __shared__ unsigned arrB[4096];              // 16 KB
    __shared__ unsigned short hist[16 * 256];    // 8 KB, flattened [bin*256 + thread]

    const int c = blockIdx.x, br = blockIdx.y, t = threadIdx.x;
    const int wv = t >> 6, l = t & 63;
    const unsigned short* src = hT + (size_t)(br * 256 + c) * 4096;

    {   // load 16 consecutive u16 per thread, build keys
        uint4 a = ((const uint4*)src)[t * 2];
        uint4 b = ((const uint4*)src)[t * 2 + 1];
        unsigned base = t * 16;
        unsigned w[8] = {a.x, a.y, a.z, a.w, b.x, b.y, b.z, b.w};
#pragma unroll
        for (int m = 0; m < 8; m++) {
            arrA[base + 2 * m]     = ((w[m] & 0xFFFFu) << 16) | (base + 2 * m);
            arrA[base + 2 * m + 1] = (w[m] & 0xFFFF0000u)     | (base + 2 * m + 1);
        }
    }
    __syncthreads();

    unsigned* A = arrA;
    unsigned* B = arrB;
#pragma unroll
    for (int pass = 0; pass < 4; pass++) {
        const int sh = 16 + pass * 4;
        unsigned keys[16];
        unsigned short cnt[16];
#pragma unroll
        for (int b = 0; b < 16; b++) cnt[b] = 0;
#pragma unroll
        for (int m = 0; m < 16; m++) {
            keys[m] = A[t * 16 + m];
            cnt[(keys[m] >> sh) & 15u]++;
        }
#pragma unroll
        for (int b = 0; b < 16; b++) hist[b * 256 + t] = cnt[b];
        __syncthreads();

        // exclusive scan of the flattened 4096-entry histogram
        unsigned loc[16];
        unsigned sum = 0;
#pragma unroll
        for (int m = 0; m < 16; m++) { loc[m] = sum; sum += hist[t * 16 + m]; }
        unsigned ws = sum;
#pragma unroll
        for (int off = 1; off < 64; off <<= 1) {
            unsigned n = __shfl_up(ws, off);
            if (l >= off) ws += n;
        }
        if (l == 63) B[wv] = ws;     // park wave sum in scatter dest (free here)
        __syncthreads();
        unsigned wbase = 0;
#pragma unroll
        for (int w2 = 0; w2 < 4; w2++) if (w2 < wv) wbase += B[w2];
        const unsigned ex = wbase + ws - sum;
#pragma unroll
        for (int m = 0; m < 16; m++) hist[t * 16 + m] = (unsigned short)(ex + loc[m]);
        __syncthreads();

        // deterministic scatter via register offsets
        unsigned offs[16];
#pragma unroll
        for (int b = 0; b < 16; b++) offs[b] = hist[b * 256 + t];
#pragma unroll
        for (int m = 0; m < 16; m++) {
            unsigned b = (keys[m] >> sh) & 15u;
            B[offs[b]++] = keys[m];
        }
        __syncthreads();
        unsigned* tmp = A; A = B; B = tmp;
    }
    // 4 passes (even) -> result back in arrA, ascending by value

    if (t < 64) {
        topkG[(br * 64 + t) * 256 + c] = arrA[4095 - t];   // descending from max
        botkG[(br * 64 + t) * 256 + c] = arrA[t];          // ascending from min
    }
}

// ---------------------------------------------------------------- probe + score
// Block: 16 edges x one branch; 4 waves x 4 edges. Lane l covers cols
// c = l + 64*sl. Probes batched 8-WIDE: 8 independent key loads then 8
// independent mask tests then priority select -- cuts the dependent-LDS
// chain ~8x vs scalar probing. Depth 0..15 from LDS; depth 16..63 from
// global top/bot-64 (L2-resident, P(reach)=2^-16 per probe); beyond that
// (P=2^-64, unreachable in practice) an exact direct scan of the hT column
// keeps correctness unconditional. LDS 40 KB. grid (256, 2), block 256.
__launch_bounds__(256)
__global__ void k_probe(const unsigned* __restrict__ topkG,
                        const unsigned* __restrict__ botkG,
                        const unsigned* __restrict__ packed,
                        const unsigned short* __restrict__ hT,
                        const float* __restrict__ Wscore,
                        const float* __restrict__ bscore,
                        float* __restrict__ out) {
    __shared__ __align__(16) unsigned topkL[16 * 256];   // [p][c] 16 KB
    __shared__ __align__(16) unsigned botkL[16 * 256];   // [p][c] 16 KB
    __shared__ __align__(16) unsigned bitsL[16 * 128];   // 8 KB

    const int t  = threadIdx.x;
    const int wv = t >> 6;
    const int l  = t & 63;
    const int e0 = blockIdx.x * 16;
    const int br = blockIdx.y;

    {
        const uint4* ts  = (const uint4*)(topkG + br * 16384);
        const uint4* bs2 = (const uint4*)(botkG + br * 16384);
#pragma unroll
        for (int m = 0; m < 4; m++) {
            ((uint4*)topkL)[t + m * 256] = ts[t + m * 256];
            ((uint4*)botkL)[t + m * 256] = bs2[t + m * 256];
        }
        ((uint4*)bitsL)[t]       = ((const uint4*)(packed + e0 * 128))[t];
        ((uint4*)bitsL)[t + 256] = ((const uint4*)(packed + e0 * 128))[t + 256];
    }
    __syncthreads();

    const float bsc = *bscore;
    float wsv[4];
#pragma unroll
    for (int sl = 0; sl < 4; sl++) wsv[sl] = Wscore[l + 64 * sl];

#pragma unroll 1
    for (int k = 0; k < 4; k++) {
        const int e = wv * 4 + k;
        const unsigned* mk = &bitsL[e * 128];
        float s = 0.f;
#pragma unroll
        for (int sl = 0; sl < 4; sl++) {
            const int c = l + 64 * sl;

            // ---- MAX: first member in descending order
            unsigned sel = 0xFFFFFFFFu;   // > any real key (value<=0x7C00)
#pragma unroll 1
            for (int g = 0; g < 2; g++) {
                unsigned kk[8]; int ss[8];
#pragma unroll
                for (int j = 0; j < 8; j++) kk[j] = topkL[(g * 8 + j) * 256 + c];
#pragma unroll
                for (int j = 0; j < 8; j++)
                    ss[j] = (int)(mk[(kk[j] & 4095u) >> 5] << (kk[j] & 31u));
                unsigned fnd = 0xFFFFFFFFu;
#pragma unroll
                for (int j = 7; j >= 0; j--) if (ss[j] < 0) fnd = kk[j];
                if (fnd != 0xFFFFFFFFu) { sel = fnd; break; }
            }
            if (sel == 0xFFFFFFFFu) {
                const unsigned* tg = topkG + br * 16384 + c;
#pragma unroll 1
                for (int p = 16; p < 64; p++) {
                    unsigned key = tg[p * 256];
                    if ((int)(mk[(key & 4095u) >> 5] << (key & 31u)) < 0) { sel = key; break; }
                }
            }
            if (sel == 0xFFFFFFFFu) {   // exact net (P=2^-64; edge nonempty via diagonal)
                const unsigned short* col = hT + (size_t)(br * 256 + c) * 4096;
                unsigned best = 0;
#pragma unroll 1
                for (int n = 0; n < 4096; n++)
                    if ((int)(mk[n >> 5] << (n & 31)) < 0) { unsigned v = col[n]; if (v > best) best = v; }
                sel = best << 16;
            }
            const float vmax = f16u_to_f(sel >> 16);

            // ---- MIN: first member in ascending order
            sel = 0xFFFFFFFFu;
#pragma unroll 1
            for (int g = 0; g < 2; g++) {
                unsigned kk[8]; int ss[8];
#pragma unroll
                for (int j = 0; j < 8; j++) kk[j] = botkL[(g * 8 + j) * 256 + c];
#pragma unroll
                for (int j = 0; j < 8; j++)
                    ss[j] = (int)(mk[(kk[j] & 4095u) >> 5] << (kk[j] & 31u));
                unsigned fnd = 0xFFFFFFFFu;
#pragma unroll
                for (int j = 7; j >= 0; j--) if (ss[j] < 0) fnd = kk[j];
                if (fnd != 0xFFFFFFFFu) { sel = fnd; break; }
            }
            if (sel == 0xFFFFFFFFu) {
                const unsigned* bg = botkG + br * 16384 + c;
#pragma unroll 1
                for (int p = 16; p < 64; p++) {
                    unsigned key = bg[p * 256];
                    if ((int)(mk[(key & 4095u) >> 5] << (key & 31u)) < 0) { sel = key; break; }
                }
            }
            if (sel == 0xFFFFFFFFu) {   // exact net
                const unsigned short* col = hT + (size_t)(br * 256 + c) * 4096;
                unsigned best = 0xFFFFu;
#pragma unroll 1
                for (int n = 0; n < 4096; n++)
                    if ((int)(mk[n >> 5] << (n & 31)) < 0) { unsigned v = col[n]; if (v < best) best = v; }
                sel = best << 16;
            }
            const float vmin = f16u_to_f(sel >> 16);

            s += (vmax - vmin) * wsv[sl];
        }
#pragma unroll
        for (int off = 32; off; off >>= 1) s += __shfl_xor(s, off);
        if (l == 0)
            out[br * 4096 + e0 + e] = 1.f / (1.f + __expf(-(s + bsc)));
    }
}

// ================================================================ fallback
// Round-13 proven pool (brute-force member-skip scan) for small-ws safety.
#define POOL_STEP(WE, MX0, MX1, MN0, MN1, VX, VY)                          \
    {                                                                      \
        asm("s_add_u32 %[we], %[we], %[we]\n\t"                            \
            "s_cbranch_scc0 Lskip%=\n\t"                                   \
            "v_pk_max_i16 %[mx0], %[mx0], %[vx]\n\t"                       \
            "v_pk_max_i16 %[mx1], %[mx1], %[vy]\n\t"                       \
            "v_pk_min_u16 %[mn0], %[mn0], %[vx]\n\t"                       \
            "v_pk_min_u16 %[mn1], %[mn1], %[vy]\n"                         \
            "Lskip%=:"                                                     \
            : [we] "+s"(WE),                                               \
              [mx0] "+v"(MX0), [mx1] "+v"(MX1),                            \
              [mn0] "+v"(MN0), [mn1] "+v"(MN1)                             \
            : [vx] "v"(VX), [vy] "v"(VY)                                   \
            : "scc");                                                      \
    }

__launch_bounds__(512, 8)
__global__ void k_pool9(const unsigned short* __restrict__ hAll,
                        const unsigned* __restrict__ packed,
                        const float* __restrict__ Wscore,
                        const float* __restrict__ bscore,
                        float* __restrict__ out) {
    __shared__ __align__(16) unsigned bits[4 * 128];
    __shared__ __align__(16) unsigned part[8][4][64][4];

    const int t  = threadIdx.x;
    const int wv = t >> 6;
    const int l  = t & 63;
    const int e0 = blockIdx.x * 4;
    const int br = blockIdx.y;
    const unsigned short* h = hAll + (size_t)br * 4096 * 256;

    if (t < 128) ((uint4*)bits)[t] = ((const uint4*)(packed + e0 * 128))[t];
    __syncthreads();

    unsigned mx0[4], mx1[4], mn0[4], mn1[4];
#pragma unroll
    for (int e = 0; e < 4; e++) {
        mx0[e] = 0x80008000u; mx1[e] = 0x80008000u;
        mn0[e] = 0xFFFFFFFFu; mn1[e] = 0xFFFFFFFFu;
    }

#pragma unroll 1
    for (int ch = 0; ch < 16; ch++) {
        const int w0 = wv * 16 + ch;
        unsigned we0 = (unsigned)__builtin_amdgcn_readfirstlane((int)bits[0 * 128 + w0]);
        unsigned we1 = (unsigned)__builtin_amdgcn_readfirstlane((int)bits[1 * 128 + w0]);
        unsigned we2 = (unsigned)__builtin_amdgcn_readfirstlane((int)bits[2 * 128 + w0]);
        unsigned we3 = (unsigned)__builtin_amdgcn_readfirstlane((int)bits[3 * 128 + w0]);

        const unsigned short* hp = h + (size_t)(wv * 512 + ch * 32) * 256 + 4 * l;
#pragma unroll
        for (int jj = 0; jj < 8; jj++) {
            uint2 v0 = *(const uint2*)(hp + (jj * 4 + 0) * 256);
            uint2 v1 = *(const uint2*)(hp + (jj * 4 + 1) * 256);
            uint2 v2 = *(const uint2*)(hp + (jj * 4 + 2) * 256);
            uint2 v3 = *(const uint2*)(hp + (jj * 4 + 3) * 256);

            POOL_STEP(we0, mx0[0], mx1[0], mn0[0], mn1[0], v0.x, v0.y);
            POOL_STEP(we1, mx0[1], mx1[1], mn0[1], mn1[1], v0.x, v0.y);
            POOL_STEP(we2, mx0[2], mx1[2], mn0[2], mn1[2], v0.x, v0.y);
            POOL_STEP(we3, mx0[3], mx1[3], mn0[3], mn1[3], v0.x, v0.y);
            POOL_STEP(we0, mx0[0], mx1[0], mn0[0], mn1[0], v1.x, v1.y);
            POOL_STEP(we1, mx0[1], mx1[1], mn0[1], mn1[1], v1.x, v1.y);
            POOL_STEP(we2, mx0[2], mx1[2], mn0[2], mn1[2], v1.x, v1.y);
            POOL_STEP(we3, mx0[3], mx1[3], mn0[3], mn1[3], v1.x, v1.y);
            POOL_STEP(we0, mx0[0], mx1[0], mn0[0], mn1[0], v2.x, v2.y);
            POOL_STEP(we1, mx0[1], mx1[1], mn0[1], mn1[1], v2.x, v2.y);
            POOL_STEP(we2, mx0[2], mx1[2], mn0[2], mn1[2], v2.x, v2.y);
            POOL_STEP(we3, mx0[3], mx1[3], mn0[3], mn1[3], v2.x, v2.y);
            POOL_STEP(we0, mx0[0], mx1[0], mn0[0], mn1[0], v3.x, v3.y);
            POOL_STEP(we1, mx0[1], mx1[1], mn0[1], mn1[1], v3.x, v3.y);
            POOL_STEP(we2, mx0[2], mx1[2], mn0[2], mn1[2], v3.x, v3.y);
            POOL_STEP(we3, mx0[3], mx1[3], mn0[3], mn1[3], v3.x, v3.y);
        }
    }

#pragma unroll
    for (int e = 0; e < 4; e++) {
        uint4 p; p.x = mx0[e]; p.y = mx1[e]; p.z = mn0[e]; p.w = mn1[e];
        *(uint4*)&part[wv][e][l][0] = p;
    }
    __syncthreads();

    if (wv < 4) {
        unsigned rmx0 = 0x80008000u, rmx1 = 0x80008000u;
        unsigned rmn0 = 0xFFFFFFFFu, rmn1 = 0xFFFFFFFFu;
#pragma unroll
        for (int w2 = 0; w2 < 8; w2++) {
            uint4 p = *(const uint4*)&part[w2][wv][l][0];
            rmx0 = pkmax_i16(rmx0, p.x);  rmx1 = pkmax_i16(rmx1, p.y);
            rmn0 = pkmin_u16(rmn0, p.z);  rmn1 = pkmin_u16(rmn1, p.w);
        }
        float4 wsv = *(const float4*)(Wscore + 4 * l);
        const float bsc = *bscore;
        float s = (f16u_to_f(rmx0)       - f16u_to_f(rmn0))       * wsv.x
                + (f16u_to_f(rmx0 >> 16) - f16u_to_f(rmn0 >> 16)) * wsv.y
                + (f16u_to_f(rmx1)       - f16u_to_f(rmn1))       * wsv.z
                + (f16u_to_f(rmx1 >> 16) - f16u_to_f(rmn1 >> 16)) * wsv.w;
#pragma unroll
        for (int off = 32; off; off >>= 1) s += __shfl_xor(s, off);
        if (l == 0)
            out[br * 4096 + e0 + wv] = 1.f / (1.f + __expf(-(s + bsc)));
    }
}

// ---------------------------------------------------------------- launch
extern "C" void kernel_launch(void* const* d_in, const int* in_sizes, int n_in,
                              void* d_out, int out_size, void* d_ws, size_t ws_size,
                              hipStream_t stream) {
    const float* pf  = (const float*)d_in[0];
    const float* pm  = (const float*)d_in[1];
    const float* nf  = (const float*)d_in[2];
    const float* nm  = (const float*)d_in[3];
    const int*   msk = (const int*)d_in[4];
    const float* Wsf = (const float*)d_in[5];
    const float* bsf = (const float*)d_in[6];
    const float* Whp = (const float*)d_in[7];
    const float* bhp = (const float*)d_in[8];
    const float* Wsc = (const float*)d_in[9];
    const float* bsc = (const float*)d_in[10];
    float* out = (float*)d_out;

    char* ws = (char*)d_ws;
    const size_t MB = 1024u * 1024u;
    unsigned short* hbuf  = (unsigned short*)(ws);                     // 4 MB: hT (main) or h row-major (fallback)
    unsigned*       pck   = (unsigned*)(ws + 4 * MB);                  // 2 MB  [4096][128]
    unsigned short* Wts   = (unsigned short*)(ws + 6 * MB);            // 128 KB
    unsigned short* Wth   = Wts + 256 * 256;                           // 128 KB
    unsigned*       topkG = (unsigned*)(ws + 6 * MB + 256 * 1024);     // 128 KB [2][64][256]
    unsigned*       botkG = (unsigned*)(ws + 6 * MB + 384 * 1024);     // 128 KB [2][64][256]
    const size_t need = 6 * MB + 512 * 1024;

    k_prep<<<2560, 256, 0, stream>>>(msk, pck, Wsf, Whp, Wts, Wth);

    if (ws_size >= need) {
        k_gemm_relu<<<dim3(64, 4, 2), 256, 0, stream>>>(pf, pm, nf, nm, Wts, Wth, bsf, bhp, hbuf, 1);
        k_sort<<<dim3(256, 2), 256, 0, stream>>>(hbuf, topkG, botkG);
        k_probe<<<dim3(256, 2), 256, 0, stream>>>(topkG, botkG, pck, hbuf, Wsc, bsc, out);
    } else {
        // small-ws fallback: round-13 brute-force pool (needs only ~6.25 MB)
        k_gemm_relu<<<dim3(64, 4, 2), 256, 0, stream>>>(pf, pm, nf, nm, Wts, Wth, bsf, bhp, hbuf, 0);
        k_pool9<<<dim3(1024, 2), 512, 0, stream>>>(hbuf, pck, Wsc, bsc, out);
    }
}

// Round 2
// 188.565 us; speedup vs baseline: 1.0108x; 1.0056x over previous
//
#include <hip/hip_runtime.h>
#include <hip/hip_bf16.h>
#include <hip/hip_fp16.h>

// N=4096 nodes, E=4096 hyperedges, F=256, H=256. All float tensors f32;
// batch_mask int32. out = 8192 f32: [pos_score | neg_score].
//
// R2 structure: 4 kernels, mask stream moved OFF the critical path.
//   k_prepW     : tiny W transpose to bf16 (512 KB, ~1 us; was fused with the
//                 12-us mask pack which serialized before the GEMM)
//   k_gemm_relu : MFMA GEMM, epilogue writes h transposed (hT[c][r])
//   k_sortpack  : per-column LSD radix sort AND mask bitmap pack, interleaved
//                 (mask loads issued early; 64-MB HBM stream overlaps the
//                  LDS/barrier-bound sort phases instead of a dedicated stage)
//   k_probe     : 8-wide batched probe vs LDS top/bot-16, global top/bot-64
//                 fallback, exact hT column scan as final correctness net.

typedef short bf16x8 __attribute__((ext_vector_type(8)));
typedef float f32x4 __attribute__((ext_vector_type(4)));
typedef short s16x2 __attribute__((ext_vector_type(2)));
typedef unsigned short u16x2 __attribute__((ext_vector_type(2)));

static __device__ __forceinline__ unsigned short f2bf(float f) {
    __hip_bfloat16 b = __float2bfloat16(f);
    return __builtin_bit_cast(unsigned short, b);
}
static __device__ __forceinline__ float f16u_to_f(unsigned u) {
    __half h = __builtin_bit_cast(__half, (unsigned short)(u & 0xffffu));
    return __half2float(h);
}
static __device__ __forceinline__ unsigned pkmax_i16(unsigned a, unsigned b) {
    s16x2 r = __builtin_elementwise_max(__builtin_bit_cast(s16x2, a), __builtin_bit_cast(s16x2, b));
    return __builtin_bit_cast(unsigned, r);
}
static __device__ __forceinline__ unsigned pkmin_u16(unsigned a, unsigned b) {
    u16x2 r = __builtin_elementwise_min(__builtin_bit_cast(u16x2, a), __builtin_bit_cast(u16x2, b));
    return __builtin_bit_cast(unsigned, r);
}

// ---------------------------------------------------------------- tiny W transpose
// Wt[n][k] = bf16(W[k][n]) for both weight matrices. grid (4,4,2), 256 thr.
__global__ void k_prepW(const float* __restrict__ Ws, const float* __restrict__ Wh,
                        unsigned short* __restrict__ Wts, unsigned short* __restrict__ Wth) {
    __shared__ unsigned short tile[64][65];
    const int k0 = blockIdx.x * 64, n0 = blockIdx.y * 64;
    const float* W     = blockIdx.z ? Wh : Ws;
    unsigned short* Wt = blockIdx.z ? Wth : Wts;
    const int t = threadIdx.x;
#pragma unroll
    for (int m = 0; m < 16; m++) {
        int li = t + m * 256; int r = li >> 6, c = li & 63;
        tile[r][c] = f2bf(W[(size_t)(k0 + r) * 256 + n0 + c]);
    }
    __syncthreads();
#pragma unroll
    for (int m = 0; m < 16; m++) {
        int li = t + m * 256; int c2 = li >> 6, r2 = li & 63;
        Wt[(size_t)(n0 + c2) * 256 + k0 + r2] = tile[r2][c2];
    }
}

// ---------------------------------------------------------------- standalone mask pack (fallback path only)
// packed word w: bit (31-j) = mask[w*32+j] != 0; membership test for idx:
// (int)(word << (idx&31)) < 0. grid (2048), 256 thr.
__global__ void k_pack(const int* __restrict__ mask, unsigned* __restrict__ packed) {
    const int w = blockIdx.x * 256 + threadIdx.x;
    const int* p = mask + (size_t)w * 32;
    unsigned word = 0;
#pragma unroll
    for (int j = 0; j < 32; j += 4) {
        int4 m = *(const int4*)(p + j);
        word |= (m.x != 0 ? (1u << (31 - j)) : 0u)
              | (m.y != 0 ? (1u << (30 - j)) : 0u)
              | (m.z != 0 ? (1u << (29 - j)) : 0u)
              | (m.w != 0 ? (1u << (28 - j)) : 0u);
    }
    packed[w] = word;
}

// ---------------------------------------------------------------- GEMM + relu -> f16 h
// tmode=1: write hOut TRANSPOSED as hT[br][c][r]  (main path; feeds k_sortpack)
// tmode=0: write hOut row-major   as h [br][r][c] (fallback path; feeds k_pool9)
__launch_bounds__(256)
__global__ void k_gemm_relu(const float* __restrict__ pXf, const float* __restrict__ pXm,
                            const float* __restrict__ nXf, const float* __restrict__ nXm,
                            const unsigned short* __restrict__ Wts, const unsigned short* __restrict__ Wth,
                            const float* __restrict__ bs,  const float* __restrict__ bh,
                            unsigned short* __restrict__ hOut, int tmode) {
    const int t  = threadIdx.x;
    const int wv = t >> 6;
    const int l  = t & 63;
    const int lm = l & 15;
    const int q  = l >> 4;
    const int bz = blockIdx.z;
    const float* Xf = bz ? nXf : pXf;
    const float* Xm = bz ? nXm : pXm;
    unsigned short* hb = hOut + (size_t)bz * 4096 * 256;

    const int m0 = blockIdx.x * 64 + wv * 16;
    const int n0 = blockIdx.y * 64;

    f32x4 acc[4] = {};
#pragma unroll
    for (int ks = 0; ks < 512; ks += 32) {
        const float* X           = (ks < 256) ? Xf : Xm;
        const unsigned short* Wt = (ks < 256) ? Wts : Wth;
        const int kk = (ks & 255) + q * 8;
        float4 a0 = *(const float4*)(X + (m0 + lm) * 256 + kk);
        float4 a1 = *(const float4*)(X + (m0 + lm) * 256 + kk + 4);
        bf16x8 a;
        a[0] = (short)f2bf(a0.x); a[1] = (short)f2bf(a0.y);
        a[2] = (short)f2bf(a0.z); a[3] = (short)f2bf(a0.w);
        a[4] = (short)f2bf(a1.x); a[5] = (short)f2bf(a1.y);
        a[6] = (short)f2bf(a1.z); a[7] = (short)f2bf(a1.w);
#pragma unroll
        for (int nt = 0; nt < 4; nt++) {
            bf16x8 b = *(const bf16x8*)(Wt + (n0 + nt * 16 + lm) * 256 + kk);
            acc[nt] = __builtin_amdgcn_mfma_f32_16x16x32_bf16(a, b, acc[nt], 0, 0, 0);
        }
    }
    if (tmode) {
        // C-fragment: col = n0+nt*16+lm, rows m0+q*4+i (i=0..3 contiguous).
#pragma unroll
        for (int nt = 0; nt < 4; nt++) {
            const int c = n0 + nt * 16 + lm;
            const float bsum = bs[c] + bh[c];
            ushort4 v4;
#pragma unroll
            for (int i = 0; i < 4; i++) {
                float v = acc[nt][i] + bsum;
                v = v > 0.f ? v : 0.f;   // relu => h >= +0.0 (u16-monotonic f16 bits)
                ((unsigned short*)&v4)[i] = __builtin_bit_cast(unsigned short, __float2half(v));
            }
            *(ushort4*)(hb + (size_t)c * 4096 + m0 + q * 4) = v4;
        }
    } else {
#pragma unroll
        for (int nt = 0; nt < 4; nt++) {
            const int c = n0 + nt * 16 + lm;
            const float bsum = bs[c] + bh[c];
#pragma unroll
            for (int i = 0; i < 4; i++) {
                const int r = m0 + q * 4 + i;
                float v = acc[nt][i] + bsum;
                v = v > 0.f ? v : 0.f;
                hb[(size_t)r * 256 + c] = __builtin_bit_cast(unsigned short, __float2half(v));
            }
        }
    }
}

// ---------------------------------------------------------------- per-column LSD radix sort + mask pack
// One block per (col, branch). keys = (f16bits << 16) | idx; 4 passes x
// 4-bit digits over the value field. Per-thread histograms + flattened
// exclusive scan -> stable deterministic ranks, no atomics. Emits top-64 /
// bot-64 keys per column. ADDITIONALLY packs the 64-MB int32 mask into the
// 2-MB bitmap: each thread owns 4 words (512 B of mask); loads are issued
// in two batches ahead of compute phases so the HBM stream overlaps the
// LDS/barrier-bound sort. LDS 40 KB. grid (256, 2), block 256.
__launch_bounds__(256)
__global__ void k_sortpack(const unsigned short* __restrict__ hT,
                           const int* __restrict__ mask,
                           unsigned* __restrict__ packed,
                           unsigned* __restrict__ topkG, unsigned* __restrict__ botkG) {
    __shared__ unsigned arrA[4096];              // 16 KB
    __shared__ unsigned arrB[4096];              // 16 KB
    __shared__ unsigned short hist[16 * 256];    // 8 KB, flattened [bin*256 + thread]

    const int c = blockIdx.x, br = blockIdx.y, t = threadIdx.x;
    const int wv = t >> 6, l = t & 63;
    const unsigned short* src = hT + (size_t)(br * 256 + c) * 4096;

    // ---- pack batch A: issue loads for words 0..1 (256 B/lane)
    const int gtid = (br * 256 + c) * 256 + t;            // 0..131071
    const int4* mp = (const int4*)(mask + (size_t)gtid * 128);
    int4 mr[16];
#pragma unroll
    for (int i = 0; i < 16; i++) mr[i] = mp[i];

    {   // load 16 consecutive u16 per thread, build keys
        uint4 a = ((const uint4*)src)[t * 2];
        uint4 b = ((const uint4*)src)[t * 2 + 1];
        unsigned base = t * 16;
        unsigned w[8] = {a.x, a.y, a.z, a.w, b.x, b.y, b.z, b.w};
#pragma unroll
        for (int m = 0; m < 8; m++) {
            arrA[base + 2 * m]     = ((w[m] & 0xFFFFu) << 16) | (base + 2 * m);
            arrA[base + 2 * m + 1] = (w[m] & 0xFFFF0000u)     | (base + 2 * m + 1);
        }
    }
    __syncthreads();

    // convert batch A (arrived during column load), issue batch B
    unsigned pw[4];
#pragma unroll
    for (int m = 0; m < 2; m++) {
        unsigned word = 0;
#pragma unroll
        for (int j2 = 0; j2 < 8; j2++) {
            int4 v = mr[m * 8 + j2];
            const int j = j2 * 4;
            word |= (v.x != 0 ? (1u << (31 - j)) : 0u)
                  | (v.y != 0 ? (1u << (30 - j)) : 0u)
                  | (v.z != 0 ? (1u << (29 - j)) : 0u)
                  | (v.w != 0 ? (1u << (28 - j)) : 0u);
        }
        pw[m] = word;
    }
#pragma unroll
    for (int i = 0; i < 16; i++) mr[i] = mp[16 + i];

    unsigned* A = arrA;
    unsigned* B = arrB;
    auto do_pass = [&](int sh) {
        unsigned keys[16];
        unsigned short cnt[16];
#pragma unroll
        for (int b = 0; b < 16; b++) cnt[b] = 0;
#pragma unroll
        for (int m = 0; m < 16; m++) {
            keys[m] = A[t * 16 + m];
            cnt[(keys[m] >> sh) & 15u]++;
        }
#pragma unroll
        for (int b = 0; b < 16; b++) hist[b * 256 + t] = cnt[b];
        __syncthreads();

        // exclusive scan of the flattened 4096-entry histogram
        unsigned loc[16];
        unsigned sum = 0;
#pragma unroll
        for (int m = 0; m < 16; m++) { loc[m] = sum; sum += hist[t * 16 + m]; }
        unsigned ws = sum;
#pragma unroll
        for (int off = 1; off < 64; off <<= 1) {
            unsigned n = __shfl_up(ws, off);
            if (l >= off) ws += n;
        }
        if (l == 63) B[wv] = ws;     // park wave sum in scatter dest (free here)
        __syncthreads();
        unsigned wbase = 0;
#pragma unroll
        for (int w2 = 0; w2 < 4; w2++) if (w2 < wv) wbase += B[w2];
        const unsigned ex = wbase + ws - sum;
#pragma unroll
        for (int m = 0; m < 16; m++) hist[t * 16 + m] = (unsigned short)(ex + loc[m]);
        __syncthreads();

        // deterministic scatter via register offsets
        unsigned offs[16];
#pragma unroll
        for (int b = 0; b < 16; b++) offs[b] = hist[b * 256 + t];
#pragma unroll
        for (int m = 0; m < 16; m++) {
            unsigned b = (keys[m] >> sh) & 15u;
            B[offs[b]++] = keys[m];
        }
        __syncthreads();
        unsigned* tmp = A; A = B; B = tmp;
    };

    do_pass(16);
    // convert batch B (arrived under pass 0), freeing mr before later passes
#pragma unroll
    for (int m = 0; m < 2; m++) {
        unsigned word = 0;
#pragma unroll
        for (int j2 = 0; j2 < 8; j2++) {
            int4 v = mr[m * 8 + j2];
            const int j = j2 * 4;
            word |= (v.x != 0 ? (1u << (31 - j)) : 0u)
                  | (v.y != 0 ? (1u << (30 - j)) : 0u)
                  | (v.z != 0 ? (1u << (29 - j)) : 0u)
                  | (v.w != 0 ? (1u << (28 - j)) : 0u);
        }
        pw[2 + m] = word;
    }
    do_pass(20);
    do_pass(24);
    do_pass(28);
    // 4 passes (even) -> result back in arrA, ascending by value

    if (t < 64) {
        topkG[(br * 64 + t) * 256 + c] = arrA[4095 - t];   // descending from max
        botkG[(br * 64 + t) * 256 + c] = arrA[t];          // ascending from min
    }
    *(uint4*)(packed + (size_t)gtid * 4) = make_uint4(pw[0], pw[1], pw[2], pw[3]);
}

// ---------------------------------------------------------------- probe + score
// Block: 16 edges x one branch; 4 waves x 4 edges. Lane l covers cols
// c = l + 64*sl. Probes batched 8-WIDE: 8 independent key loads then 8
// independent mask tests then priority select. Depth 0..15 from LDS;
// depth 16..63 from global top/bot-64 (L2-resident, P(reach)=2^-16 per
// probe); beyond that (P=2^-64, unreachable in practice) an exact direct
// scan of the hT column keeps correctness unconditional. LDS 40 KB.
// grid (256, 2), block 256.
__launch_bounds__(256)
__global__ void k_probe(const unsigned* __restrict__ topkG,
                        const unsigned* __restrict__ botkG,
                        const unsigned* __restrict__ packed,
                        const unsigned short* __restrict__ hT,
                        const float* __restrict__ Wscore,
                        const float* __restrict__ bscore,
                        float* __restrict__ out) {
    __shared__ __align__(16) unsigned topkL[16 * 256];   // [p][c] 16 KB
    __shared__ __align__(16) unsigned botkL[16 * 256];   // [p][c] 16 KB
    __shared__ __align__(16) unsigned bitsL[16 * 128];   // 8 KB

    const int t  = threadIdx.x;
    const int wv = t >> 6;
    const int l  = t & 63;
    const int e0 = blockIdx.x * 16;
    const int br = blockIdx.y;

    {
        const uint4* ts  = (const uint4*)(topkG + br * 16384);
        const uint4* bs2 = (const uint4*)(botkG + br * 16384);
#pragma unroll
        for (int m = 0; m < 4; m++) {
            ((uint4*)topkL)[t + m * 256] = ts[t + m * 256];
            ((uint4*)botkL)[t + m * 256] = bs2[t + m * 256];
        }
        ((uint4*)bitsL)[t]       = ((const uint4*)(packed + e0 * 128))[t];
        ((uint4*)bitsL)[t + 256] = ((const uint4*)(packed + e0 * 128))[t + 256];
    }
    __syncthreads();

    const float bsc = *bscore;
    float wsv[4];
#pragma unroll
    for (int sl = 0; sl < 4; sl++) wsv[sl] = Wscore[l + 64 * sl];

#pragma unroll 1
    for (int k = 0; k < 4; k++) {
        const int e = wv * 4 + k;
        const unsigned* mk = &bitsL[e * 128];
        float s = 0.f;
#pragma unroll
        for (int sl = 0; sl < 4; sl++) {
            const int c = l + 64 * sl;

            // ---- MAX: first member in descending order
            unsigned sel = 0xFFFFFFFFu;   // > any real key (value<=0x7C00)
#pragma unroll 1
            for (int g = 0; g < 2; g++) {
                unsigned kk[8]; int ss[8];
#pragma unroll
                for (int j = 0; j < 8; j++) kk[j] = topkL[(g * 8 + j) * 256 + c];
#pragma unroll
                for (int j = 0; j < 8; j++)
                    ss[j] = (int)(mk[(kk[j] & 4095u) >> 5] << (kk[j] & 31u));
                unsigned fnd = 0xFFFFFFFFu;
#pragma unroll
                for (int j = 7; j >= 0; j--) if (ss[j] < 0) fnd = kk[j];
                if (fnd != 0xFFFFFFFFu) { sel = fnd; break; }
            }
            if (sel == 0xFFFFFFFFu) {
                const unsigned* tg = topkG + br * 16384 + c;
#pragma unroll 1
                for (int p = 16; p < 64; p++) {
                    unsigned key = tg[p * 256];
                    if ((int)(mk[(key & 4095u) >> 5] << (key & 31u)) < 0) { sel = key; break; }
                }
            }
            if (sel == 0xFFFFFFFFu) {   // exact net (P=2^-64; edge nonempty via diagonal)
                const unsigned short* col = hT + (size_t)(br * 256 + c) * 4096;
                unsigned best = 0;
#pragma unroll 1
                for (int n = 0; n < 4096; n++)
                    if ((int)(mk[n >> 5] << (n & 31)) < 0) { unsigned v = col[n]; if (v > best) best = v; }
                sel = best << 16;
            }
            const float vmax = f16u_to_f(sel >> 16);

            // ---- MIN: first member in ascending order
            sel = 0xFFFFFFFFu;
#pragma unroll 1
            for (int g = 0; g < 2; g++) {
                unsigned kk[8]; int ss[8];
#pragma unroll
                for (int j = 0; j < 8; j++) kk[j] = botkL[(g * 8 + j) * 256 + c];
#pragma unroll
                for (int j = 0; j < 8; j++)
                    ss[j] = (int)(mk[(kk[j] & 4095u) >> 5] << (kk[j] & 31u));
                unsigned fnd = 0xFFFFFFFFu;
#pragma unroll
                for (int j = 7; j >= 0; j--) if (ss[j] < 0) fnd = kk[j];
                if (fnd != 0xFFFFFFFFu) { sel = fnd; break; }
            }
            if (sel == 0xFFFFFFFFu) {
                const unsigned* bg = botkG + br * 16384 + c;
#pragma unroll 1
                for (int p = 16; p < 64; p++) {
                    unsigned key = bg[p * 256];
                    if ((int)(mk[(key & 4095u) >> 5] << (key & 31u)) < 0) { sel = key; break; }
                }
            }
            if (sel == 0xFFFFFFFFu) {   // exact net
                const unsigned short* col = hT + (size_t)(br * 256 + c) * 4096;
                unsigned best = 0xFFFFu;
#pragma unroll 1
                for (int n = 0; n < 4096; n++)
                    if ((int)(mk[n >> 5] << (n & 31)) < 0) { unsigned v = col[n]; if (v < best) best = v; }
                sel = best << 16;
            }
            const float vmin = f16u_to_f(sel >> 16);

            s += (vmax - vmin) * wsv[sl];
        }
#pragma unroll
        for (int off = 32; off; off >>= 1) s += __shfl_xor(s, off);
        if (l == 0)
            out[br * 4096 + e0 + e] = 1.f / (1.f + __expf(-(s + bsc)));
    }
}

// ================================================================ fallback
// Round-13 proven pool (brute-force member-skip scan) for small-ws safety.
#define POOL_STEP(WE, MX0, MX1, MN0, MN1, VX, VY)                          \
    {                                                                      \
        asm("s_add_u32 %[we], %[we], %[we]\n\t"                            \
            "s_cbranch_scc0 Lskip%=\n\t"                                   \
            "v_pk_max_i16 %[mx0], %[mx0], %[vx]\n\t"                       \
            "v_pk_max_i16 %[mx1], %[mx1], %[vy]\n\t"                       \
            "v_pk_min_u16 %[mn0], %[mn0], %[vx]\n\t"                       \
            "v_pk_min_u16 %[mn1], %[mn1], %[vy]\n"                         \
            "Lskip%=:"                                                     \
            : [we] "+s"(WE),                                               \
              [mx0] "+v"(MX0), [mx1] "+v"(MX1),                            \
              [mn0] "+v"(MN0), [mn1] "+v"(MN1)                             \
            : [vx] "v"(VX), [vy] "v"(VY)                                   \
            : "scc");                                                      \
    }

__launch_bounds__(512, 8)
__global__ void k_pool9(const unsigned short* __restrict__ hAll,
                        const unsigned* __restrict__ packed,
                        const float* __restrict__ Wscore,
                        const float* __restrict__ bscore,
                        float* __restrict__ out) {
    __shared__ __align__(16) unsigned bits[4 * 128];
    __shared__ __align__(16) unsigned part[8][4][64][4];

    const int t  = threadIdx.x;
    const int wv = t >> 6;
    const int l  = t & 63;
    const int e0 = blockIdx.x * 4;
    const int br = blockIdx.y;
    const unsigned short* h = hAll + (size_t)br * 4096 * 256;

    if (t < 128) ((uint4*)bits)[t] = ((const uint4*)(packed + e0 * 128))[t];
    __syncthreads();

    unsigned mx0[4], mx1[4], mn0[4], mn1[4];
#pragma unroll
    for (int e = 0; e < 4; e++) {
        mx0[e] = 0x80008000u; mx1[e] = 0x80008000u;
        mn0[e] = 0xFFFFFFFFu; mn1[e] = 0xFFFFFFFFu;
    }

#pragma unroll 1
    for (int ch = 0; ch < 16; ch++) {
        const int w0 = wv * 16 + ch;
        unsigned we0 = (unsigned)__builtin_amdgcn_readfirstlane((int)bits[0 * 128 + w0]);
        unsigned we1 = (unsigned)__builtin_amdgcn_readfirstlane((int)bits[1 * 128 + w0]);
        unsigned we2 = (unsigned)__builtin_amdgcn_readfirstlane((int)bits[2 * 128 + w0]);
        unsigned we3 = (unsigned)__builtin_amdgcn_readfirstlane((int)bits[3 * 128 + w0]);

        const unsigned short* hp = h + (size_t)(wv * 512 + ch * 32) * 256 + 4 * l;
#pragma unroll
        for (int jj = 0; jj < 8; jj++) {
            uint2 v0 = *(const uint2*)(hp + (jj * 4 + 0) * 256);
            uint2 v1 = *(const uint2*)(hp + (jj * 4 + 1) * 256);
            uint2 v2 = *(const uint2*)(hp + (jj * 4 + 2) * 256);
            uint2 v3 = *(const uint2*)(hp + (jj * 4 + 3) * 256);

            POOL_STEP(we0, mx0[0], mx1[0], mn0[0], mn1[0], v0.x, v0.y);
            POOL_STEP(we1, mx0[1], mx1[1], mn0[1], mn1[1], v0.x, v0.y);
            POOL_STEP(we2, mx0[2], mx1[2], mn0[2], mn1[2], v0.x, v0.y);
            POOL_STEP(we3, mx0[3], mx1[3], mn0[3], mn1[3], v0.x, v0.y);
            POOL_STEP(we0, mx0[0], mx1[0], mn0[0], mn1[0], v1.x, v1.y);
            POOL_STEP(we1, mx0[1], mx1[1], mn0[1], mn1[1], v1.x, v1.y);
            POOL_STEP(we2, mx0[2], mx1[2], mn0[2], mn1[2], v1.x, v1.y);
            POOL_STEP(we3, mx0[3], mx1[3], mn0[3], mn1[3], v1.x, v1.y);
            POOL_STEP(we0, mx0[0], mx1[0], mn0[0], mn1[0], v2.x, v2.y);
            POOL_STEP(we1, mx0[1], mx1[1], mn0[1], mn1[1], v2.x, v2.y);
            POOL_STEP(we2, mx0[2], mx1[2], mn0[2], mn1[2], v2.x, v2.y);
            POOL_STEP(we3, mx0[3], mx1[3], mn0[3], mn1[3], v2.x, v2.y);
            POOL_STEP(we0, mx0[0], mx1[0], mn0[0], mn1[0], v3.x, v3.y);
            POOL_STEP(we1, mx0[1], mx1[1], mn0[1], mn1[1], v3.x, v3.y);
            POOL_STEP(we2, mx0[2], mx1[2], mn0[2], mn1[2], v3.x, v3.y);
            POOL_STEP(we3, mx0[3], mx1[3], mn0[3], mn1[3], v3.x, v3.y);
        }
    }

#pragma unroll
    for (int e = 0; e < 4; e++) {
        uint4 p; p.x = mx0[e]; p.y = mx1[e]; p.z = mn0[e]; p.w = mn1[e];
        *(uint4*)&part[wv][e][l][0] = p;
    }
    __syncthreads();

    if (wv < 4) {
        unsigned rmx0 = 0x80008000u, rmx1 = 0x80008000u;
        unsigned rmn0 = 0xFFFFFFFFu, rmn1 = 0xFFFFFFFFu;
#pragma unroll
        for (int w2 = 0; w2 < 8; w2++) {
            uint4 p = *(const uint4*)&part[w2][wv][l][0];
            rmx0 = pkmax_i16(rmx0, p.x);  rmx1 = pkmax_i16(rmx1, p.y);
            rmn0 = pkmin_u16(rmn0, p.z);  rmn1 = pkmin_u16(rmn1, p.w);
        }
        float4 wsv = *(const float4*)(Wscore + 4 * l);
        const float bsc = *bscore;
        float s = (f16u_to_f(rmx0)       - f16u_to_f(rmn0))       * wsv.x
                + (f16u_to_f(rmx0 >> 16) - f16u_to_f(rmn0 >> 16)) * wsv.y
                + (f16u_to_f(rmx1)       - f16u_to_f(rmn1))       * wsv.z
                + (f16u_to_f(rmx1 >> 16) - f16u_to_f(rmn1 >> 16)) * wsv.w;
#pragma unroll
        for (int off = 32; off; off >>= 1) s += __shfl_xor(s, off);
        if (l == 0)
            out[br * 4096 + e0 + wv] = 1.f / (1.f + __expf(-(s + bsc)));
    }
}

// ---------------------------------------------------------------- launch
extern "C" void kernel_launch(void* const* d_in, const int* in_sizes, int n_in,
                              void* d_out, int out_size, void* d_ws, size_t ws_size,
                              hipStream_t stream) {
    const float* pf  = (const float*)d_in[0];
    const float* pm  = (const float*)d_in[1];
    const float* nf  = (const float*)d_in[2];
    const float* nm  = (const float*)d_in[3];
    const int*   msk = (const int*)d_in[4];
    const float* Wsf = (const float*)d_in[5];
    const float* bsf = (const float*)d_in[6];
    const float* Whp = (const float*)d_in[7];
    const float* bhp = (const float*)d_in[8];
    const float* Wsc = (const float*)d_in[9];
    const float* bsc = (const float*)d_in[10];
    float* out = (float*)d_out;

    char* ws = (char*)d_ws;
    const size_t MB = 1024u * 1024u;
    unsigned short* hbuf  = (unsigned short*)(ws);                     // 4 MB: hT (main) or h row-major (fallback)
    unsigned*       pck   = (unsigned*)(ws + 4 * MB);                  // 2 MB  [4096][128]
    unsigned short* Wts   = (unsigned short*)(ws + 6 * MB);            // 128 KB
    unsigned short* Wth   = Wts + 256 * 256;                           // 128 KB
    unsigned*       topkG = (unsigned*)(ws + 6 * MB + 256 * 1024);     // 128 KB [2][64][256]
    unsigned*       botkG = (unsigned*)(ws + 6 * MB + 384 * 1024);     // 128 KB [2][64][256]
    const size_t need = 6 * MB + 512 * 1024;

    k_prepW<<<dim3(4, 4, 2), 256, 0, stream>>>(Wsf, Whp, Wts, Wth);

    if (ws_size >= need) {
        k_gemm_relu<<<dim3(64, 4, 2), 256, 0, stream>>>(pf, pm, nf, nm, Wts, Wth, bsf, bhp, hbuf, 1);
        k_sortpack<<<dim3(256, 2), 256, 0, stream>>>(hbuf, msk, pck, topkG, botkG);
        k_probe<<<dim3(256, 2), 256, 0, stream>>>(topkG, botkG, pck, hbuf, Wsc, bsc, out);
    } else {
        // small-ws fallback: round-13 brute-force pool (needs only ~6.25 MB)
        k_pack<<<2048, 256, 0, stream>>>(msk, pck);
        k_gemm_relu<<<dim3(64, 4, 2), 256, 0, stream>>>(pf, pm, nf, nm, Wts, Wth, bsf, bhp, hbuf, 0);
        k_pool9<<<dim3(1024, 2), 512, 0, stream>>>(hbuf, pck, Wsc, bsc, out);
    }
}

// Round 4
// 175.055 us; speedup vs baseline: 1.0888x; 1.0772x over previous
//
#include <hip/hip_runtime.h>
#include <hip/hip_bf16.h>
#include <hip/hip_fp16.h>

// N=4096 nodes, E=4096 hyperedges, F=256, H=256. All float tensors f32;
// batch_mask int32. out = 8192 f32: [pos_score | neg_score].
//
// R4 = R3 with the scan-coverage bug fixed:
//   histogram is 16 bins x 512 threads = 8192 entries; the flattened
//   exclusive scan must cover 16 entries/thread (t*16+m), not 8 (R3 only
//   scanned the first 4096 slots, leaving bins 8..15 as raw counts ->
//   bogus scatter ranks -> corrupted sort).
// k_sortpack (dominant kernel at ~41 us in R2):
//   - 512 threads/block, 8 keys/thread
//   - digit counters nibble-packed in 2 scalars -> NO runtime-indexed arrays
//   - scatter rank = hist[digit] + match-count of earlier same-digit elems
//   - key arrays padded +1/16, hist padded +1/8 (bank-conflict breakers)
//   - pass 0 consumes keys straight from registers
//   - mask bitmap pack fused/overlapped (2 words/thread, 2 batches)

typedef short bf16x8 __attribute__((ext_vector_type(8)));
typedef float f32x4 __attribute__((ext_vector_type(4)));
typedef short s16x2 __attribute__((ext_vector_type(2)));
typedef unsigned short u16x2 __attribute__((ext_vector_type(2)));

static __device__ __forceinline__ unsigned short f2bf(float f) {
    __hip_bfloat16 b = __float2bfloat16(f);
    return __builtin_bit_cast(unsigned short, b);
}
static __device__ __forceinline__ float f16u_to_f(unsigned u) {
    __half h = __builtin_bit_cast(__half, (unsigned short)(u & 0xffffu));
    return __half2float(h);
}
static __device__ __forceinline__ unsigned pkmax_i16(unsigned a, unsigned b) {
    s16x2 r = __builtin_elementwise_max(__builtin_bit_cast(s16x2, a), __builtin_bit_cast(s16x2, b));
    return __builtin_bit_cast(unsigned, r);
}
static __device__ __forceinline__ unsigned pkmin_u16(unsigned a, unsigned b) {
    u16x2 r = __builtin_elementwise_min(__builtin_bit_cast(u16x2, a), __builtin_bit_cast(u16x2, b));
    return __builtin_bit_cast(unsigned, r);
}
// padded index maps (bank-conflict breakers)
static __device__ __forceinline__ int fpad(int i) { return i + (i >> 4); }  // key arrays: +1 word per 16
static __device__ __forceinline__ int fh(int i)   { return i + (i >> 3); }  // hist: +1 entry per 8

// ---------------------------------------------------------------- tiny W transpose
// Wt[n][k] = bf16(W[k][n]) for both weight matrices. grid (4,4,2), 256 thr.
__global__ void k_prepW(const float* __restrict__ Ws, const float* __restrict__ Wh,
                        unsigned short* __restrict__ Wts, unsigned short* __restrict__ Wth) {
    __shared__ unsigned short tile[64][65];
    const int k0 = blockIdx.x * 64, n0 = blockIdx.y * 64;
    const float* W     = blockIdx.z ? Wh : Ws;
    unsigned short* Wt = blockIdx.z ? Wth : Wts;
    const int t = threadIdx.x;
#pragma unroll
    for (int m = 0; m < 16; m++) {
        int li = t + m * 256; int r = li >> 6, c = li & 63;
        tile[r][c] = f2bf(W[(size_t)(k0 + r) * 256 + n0 + c]);
    }
    __syncthreads();
#pragma unroll
    for (int m = 0; m < 16; m++) {
        int li = t + m * 256; int c2 = li >> 6, r2 = li & 63;
        Wt[(size_t)(n0 + c2) * 256 + k0 + r2] = tile[r2][c2];
    }
}

// ---------------------------------------------------------------- standalone mask pack (fallback path only)
__global__ void k_pack(const int* __restrict__ mask, unsigned* __restrict__ packed) {
    const int w = blockIdx.x * 256 + threadIdx.x;
    const int* p = mask + (size_t)w * 32;
    unsigned word = 0;
#pragma unroll
    for (int j = 0; j < 32; j += 4) {
        int4 m = *(const int4*)(p + j);
        word |= (m.x != 0 ? (1u << (31 - j)) : 0u)
              | (m.y != 0 ? (1u << (30 - j)) : 0u)
              | (m.z != 0 ? (1u << (29 - j)) : 0u)
              | (m.w != 0 ? (1u << (28 - j)) : 0u);
    }
    packed[w] = word;
}

// ---------------------------------------------------------------- GEMM + relu -> f16 h
// tmode=1: write hOut TRANSPOSED as hT[br][c][r]  (main path; feeds k_sortpack)
// tmode=0: write hOut row-major   as h [br][r][c] (fallback path; feeds k_pool9)
__launch_bounds__(256)
__global__ void k_gemm_relu(const float* __restrict__ pXf, const float* __restrict__ pXm,
                            const float* __restrict__ nXf, const float* __restrict__ nXm,
                            const unsigned short* __restrict__ Wts, const unsigned short* __restrict__ Wth,
                            const float* __restrict__ bs,  const float* __restrict__ bh,
                            unsigned short* __restrict__ hOut, int tmode) {
    const int t  = threadIdx.x;
    const int wv = t >> 6;
    const int l  = t & 63;
    const int lm = l & 15;
    const int q  = l >> 4;
    const int bz = blockIdx.z;
    const float* Xf = bz ? nXf : pXf;
    const float* Xm = bz ? nXm : pXm;
    unsigned short* hb = hOut + (size_t)bz * 4096 * 256;

    const int m0 = blockIdx.x * 64 + wv * 16;
    const int n0 = blockIdx.y * 64;

    f32x4 acc[4] = {};
#pragma unroll
    for (int ks = 0; ks < 512; ks += 32) {
        const float* X           = (ks < 256) ? Xf : Xm;
        const unsigned short* Wt = (ks < 256) ? Wts : Wth;
        const int kk = (ks & 255) + q * 8;
        float4 a0 = *(const float4*)(X + (m0 + lm) * 256 + kk);
        float4 a1 = *(const float4*)(X + (m0 + lm) * 256 + kk + 4);
        bf16x8 a;
        a[0] = (short)f2bf(a0.x); a[1] = (short)f2bf(a0.y);
        a[2] = (short)f2bf(a0.z); a[3] = (short)f2bf(a0.w);
        a[4] = (short)f2bf(a1.x); a[5] = (short)f2bf(a1.y);
        a[6] = (short)f2bf(a1.z); a[7] = (short)f2bf(a1.w);
#pragma unroll
        for (int nt = 0; nt < 4; nt++) {
            bf16x8 b = *(const bf16x8*)(Wt + (n0 + nt * 16 + lm) * 256 + kk);
            acc[nt] = __builtin_amdgcn_mfma_f32_16x16x32_bf16(a, b, acc[nt], 0, 0, 0);
        }
    }
    if (tmode) {
#pragma unroll
        for (int nt = 0; nt < 4; nt++) {
            const int c = n0 + nt * 16 + lm;
            const float bsum = bs[c] + bh[c];
            ushort4 v4;
#pragma unroll
            for (int i = 0; i < 4; i++) {
                float v = acc[nt][i] + bsum;
                v = v > 0.f ? v : 0.f;   // relu => h >= +0.0 (u16-monotonic f16 bits)
                ((unsigned short*)&v4)[i] = __builtin_bit_cast(unsigned short, __float2half(v));
            }
            *(ushort4*)(hb + (size_t)c * 4096 + m0 + q * 4) = v4;
        }
    } else {
#pragma unroll
        for (int nt = 0; nt < 4; nt++) {
            const int c = n0 + nt * 16 + lm;
            const float bsum = bs[c] + bh[c];
#pragma unroll
            for (int i = 0; i < 4; i++) {
                const int r = m0 + q * 4 + i;
                float v = acc[nt][i] + bsum;
                v = v > 0.f ? v : 0.f;
                hb[(size_t)r * 256 + c] = __builtin_bit_cast(unsigned short, __float2half(v));
            }
        }
    }
}

// ---------------------------------------------------------------- per-column LSD radix sort + mask pack
// One block per (col, branch), 512 threads, 8 keys/thread. keys =
// (f16bits<<16)|idx; 4 stable passes x 4-bit digits over the value field.
// Histogram = 16 bins x 512 threads = 8192 entries; scan covers 16
// entries/thread (FIXED: R3 scanned only 8 -> bins 8..15 unscanned).
// No runtime-indexed register arrays; counts nibble-packed in 2 u32;
// scatter rank = hist-base + unrolled match-count. Padded LDS (fpad/fh).
// Emits top-64/bot-64 per column + packs the mask bitmap. LDS 52 KB.
// grid (256, 2), block 512.
__launch_bounds__(512)
__global__ void k_sortpack(const unsigned short* __restrict__ hT,
                           const int* __restrict__ mask,
                           unsigned* __restrict__ packed,
                           unsigned* __restrict__ topkG, unsigned* __restrict__ botkG) {
    __shared__ unsigned arrA[4352];              // 4096 + 256 pad = 17 KB
    __shared__ unsigned arrB[4352];              // 17 KB
    __shared__ unsigned short hist[9216];        // 8192 + 1024 pad = 18 KB

    const int c = blockIdx.x, br = blockIdx.y, t = threadIdx.x;
    const int wv = t >> 6, l = t & 63;
    const unsigned short* src = hT + (size_t)(br * 256 + c) * 4096;

    // mask pack: thread owns packed words 2*gt, 2*gt+1
    const int gt = (br * 256 + c) * 512 + t;
    const int4* mp = (const int4*)(mask + (size_t)gt * 64);
    int4 mr[8];
#pragma unroll
    for (int i = 0; i < 8; i++) mr[i] = mp[i];          // batch 0 (word 2*gt)

    // build keys in registers (8 consecutive u16 from the column)
    unsigned keys[8];
    {
        uint4 a = ((const uint4*)src)[t];
        unsigned base = t * 8;
        unsigned w[4] = {a.x, a.y, a.z, a.w};
#pragma unroll
        for (int m = 0; m < 4; m++) {
            keys[2 * m]     = ((w[m] & 0xFFFFu) << 16) | (base + 2 * m);
            keys[2 * m + 1] = (w[m] & 0xFFFF0000u)     | (base + 2 * m + 1);
        }
    }

    auto cvt = [&]() -> unsigned {
        unsigned word = 0;
#pragma unroll
        for (int j2 = 0; j2 < 8; j2++) {
            int4 v = mr[j2];
            const int j = j2 * 4;
            word |= (v.x != 0 ? (1u << (31 - j)) : 0u)
                  | (v.y != 0 ? (1u << (30 - j)) : 0u)
                  | (v.z != 0 ? (1u << (29 - j)) : 0u)
                  | (v.w != 0 ? (1u << (28 - j)) : 0u);
        }
        return word;
    };

    auto sort_pass = [&](int sh, unsigned* Bp) {
        unsigned d[8];
        unsigned c0 = 0, c1 = 0;
#pragma unroll
        for (int m = 0; m < 8; m++) {
            d[m] = (keys[m] >> sh) & 15u;
            unsigned inc = 1u << ((d[m] & 7u) * 4);
            if (d[m] < 8u) c0 += inc; else c1 += inc;   // nibble-packed counts (max 8 fits)
        }
#pragma unroll
        for (int b = 0; b < 8; b++) hist[fh(b * 512 + t)]       = (unsigned short)((c0 >> (b * 4)) & 15u);
#pragma unroll
        for (int b = 0; b < 8; b++) hist[fh((b + 8) * 512 + t)] = (unsigned short)((c1 >> (b * 4)) & 15u);
        __syncthreads();

        // flattened exclusive scan of the 8192-entry histogram: 16/thread
        unsigned loc[16];
        unsigned sum = 0;
#pragma unroll
        for (int m = 0; m < 16; m++) { loc[m] = sum; sum += hist[fh(t * 16 + m)]; }
        unsigned ws = sum;
#pragma unroll
        for (int off = 1; off < 64; off <<= 1) {
            unsigned n = __shfl_up(ws, off);
            if (l >= off) ws += n;
        }
        if (l == 63) Bp[wv] = ws;     // park wave sums in scatter dest (free here)
        __syncthreads();
        unsigned wbase = 0;
#pragma unroll
        for (int w2 = 0; w2 < 8; w2++) if (w2 < wv) wbase += Bp[w2];
        const unsigned ex = wbase + ws - sum;
#pragma unroll
        for (int m = 0; m < 16; m++) hist[fh(t * 16 + m)] = (unsigned short)(ex + loc[m]);
        __syncthreads();

        // scatter: rank = per-(digit,thread) base + count of earlier same-digit elems
#pragma unroll
        for (int m = 0; m < 8; m++) {
            unsigned rank = hist[fh((int)d[m] * 512 + t)];
            unsigned prior = 0;
#pragma unroll
            for (int j = 0; j < m; j++) prior += (d[j] == d[m]) ? 1u : 0u;
            Bp[fpad((int)(rank + prior))] = keys[m];
        }
        __syncthreads();
    };

    auto load_keys = [&](const unsigned* Ap) {
        const unsigned* ap = Ap + t * 8 + (t >> 1);     // fpad(t*8) contiguous run
#pragma unroll
        for (int m = 0; m < 8; m++) keys[m] = ap[m];
    };

    const unsigned pw0 = cvt();                          // batch 0 arrived under key load
#pragma unroll
    for (int i = 0; i < 8; i++) mr[i] = mp[8 + i];       // issue batch 1 (word 2*gt+1)

    sort_pass(16, arrB);                                 // pass 0: keys from registers
    const unsigned pw1 = cvt();                          // batch 1 arrived under pass 0
    load_keys(arrB); sort_pass(20, arrA);
    load_keys(arrA); sort_pass(24, arrB);
    load_keys(arrB); sort_pass(28, arrA);
    // 4 stable passes -> arrA ascending by value (idx rides along, unique keys)

    if (t < 64) {
        topkG[(br * 64 + t) * 256 + c] = arrA[fpad(4095 - t)];   // descending from max
        botkG[(br * 64 + t) * 256 + c] = arrA[fpad(t)];          // ascending from min
    }
    *(uint2*)(packed + (size_t)gt * 2) = make_uint2(pw0, pw1);
}

// ---------------------------------------------------------------- probe + score
// Block: 16 edges x one branch; 4 waves x 4 edges. Lane l covers cols
// c = l + 64*sl. Probes batched 8-WIDE. Depth 0..15 from LDS; depth 16..63
// from global top/bot-64 (P(reach)=2^-16 per probe); beyond that (P=2^-64)
// an exact direct scan of the hT column keeps correctness unconditional.
// LDS 40 KB. grid (256, 2), block 256.
__launch_bounds__(256)
__global__ void k_probe(const unsigned* __restrict__ topkG,
                        const unsigned* __restrict__ botkG,
                        const unsigned* __restrict__ packed,
                        const unsigned short* __restrict__ hT,
                        const float* __restrict__ Wscore,
                        const float* __restrict__ bscore,
                        float* __restrict__ out) {
    __shared__ __align__(16) unsigned topkL[16 * 256];   // [p][c] 16 KB
    __shared__ __align__(16) unsigned botkL[16 * 256];   // [p][c] 16 KB
    __shared__ __align__(16) unsigned bitsL[16 * 128];   // 8 KB

    const int t  = threadIdx.x;
    const int wv = t >> 6;
    const int l  = t & 63;
    const int e0 = blockIdx.x * 16;
    const int br = blockIdx.y;

    {
        const uint4* ts  = (const uint4*)(topkG + br * 16384);
        const uint4* bs2 = (const uint4*)(botkG + br * 16384);
#pragma unroll
        for (int m = 0; m < 4; m++) {
            ((uint4*)topkL)[t + m * 256] = ts[t + m * 256];
            ((uint4*)botkL)[t + m * 256] = bs2[t + m * 256];
        }
        ((uint4*)bitsL)[t]       = ((const uint4*)(packed + e0 * 128))[t];
        ((uint4*)bitsL)[t + 256] = ((const uint4*)(packed + e0 * 128))[t + 256];
    }
    __syncthreads();

    const float bsc = *bscore;
    float wsv[4];
#pragma unroll
    for (int sl = 0; sl < 4; sl++) wsv[sl] = Wscore[l + 64 * sl];

#pragma unroll 1
    for (int k = 0; k < 4; k++) {
        const int e = wv * 4 + k;
        const unsigned* mk = &bitsL[e * 128];
        float s = 0.f;
#pragma unroll
        for (int sl = 0; sl < 4; sl++) {
            const int c = l + 64 * sl;

            // ---- MAX: first member in descending order
            unsigned sel = 0xFFFFFFFFu;   // > any real key (value<=0x7C00)
#pragma unroll 1
            for (int g = 0; g < 2; g++) {
                unsigned kk[8]; int ss[8];
#pragma unroll
                for (int j = 0; j < 8; j++) kk[j] = topkL[(g * 8 + j) * 256 + c];
#pragma unroll
                for (int j = 0; j < 8; j++)
                    ss[j] = (int)(mk[(kk[j] & 4095u) >> 5] << (kk[j] & 31u));
                unsigned fnd = 0xFFFFFFFFu;
#pragma unroll
                for (int j = 7; j >= 0; j--) if (ss[j] < 0) fnd = kk[j];
                if (fnd != 0xFFFFFFFFu) { sel = fnd; break; }
            }
            if (sel == 0xFFFFFFFFu) {
                const unsigned* tg = topkG + br * 16384 + c;
#pragma unroll 1
                for (int p = 16; p < 64; p++) {
                    unsigned key = tg[p * 256];
                    if ((int)(mk[(key & 4095u) >> 5] << (key & 31u)) < 0) { sel = key; break; }
                }
            }
            if (sel == 0xFFFFFFFFu) {   // exact net (P=2^-64; edge nonempty via diagonal)
                const unsigned short* col = hT + (size_t)(br * 256 + c) * 4096;
                unsigned best = 0;
#pragma unroll 1
                for (int n = 0; n < 4096; n++)
                    if ((int)(mk[n >> 5] << (n & 31)) < 0) { unsigned v = col[n]; if (v > best) best = v; }
                sel = best << 16;
            }
            const float vmax = f16u_to_f(sel >> 16);

            // ---- MIN: first member in ascending order
            sel = 0xFFFFFFFFu;
#pragma unroll 1
            for (int g = 0; g < 2; g++) {
                unsigned kk[8]; int ss[8];
#pragma unroll
                for (int j = 0; j < 8; j++) kk[j] = botkL[(g * 8 + j) * 256 + c];
#pragma unroll
                for (int j = 0; j < 8; j++)
                    ss[j] = (int)(mk[(kk[j] & 4095u) >> 5] << (kk[j] & 31u));
                unsigned fnd = 0xFFFFFFFFu;
#pragma unroll
                for (int j = 7; j >= 0; j--) if (ss[j] < 0) fnd = kk[j];
                if (fnd != 0xFFFFFFFFu) { sel = fnd; break; }
            }
            if (sel == 0xFFFFFFFFu) {
                const unsigned* bg = botkG + br * 16384 + c;
#pragma unroll 1
                for (int p = 16; p < 64; p++) {
                    unsigned key = bg[p * 256];
                    if ((int)(mk[(key & 4095u) >> 5] << (key & 31u)) < 0) { sel = key; break; }
                }
            }
            if (sel == 0xFFFFFFFFu) {   // exact net
                const unsigned short* col = hT + (size_t)(br * 256 + c) * 4096;
                unsigned best = 0xFFFFu;
#pragma unroll 1
                for (int n = 0; n < 4096; n++)
                    if ((int)(mk[n >> 5] << (n & 31)) < 0) { unsigned v = col[n]; if (v < best) best = v; }
                sel = best << 16;
            }
            const float vmin = f16u_to_f(sel >> 16);

            s += (vmax - vmin) * wsv[sl];
        }
#pragma unroll
        for (int off = 32; off; off >>= 1) s += __shfl_xor(s, off);
        if (l == 0)
            out[br * 4096 + e0 + e] = 1.f / (1.f + __expf(-(s + bsc)));
    }
}

// ================================================================ fallback
// Round-13 proven pool (brute-force member-skip scan) for small-ws safety.
#define POOL_STEP(WE, MX0, MX1, MN0, MN1, VX, VY)                          \
    {                                                                      \
        asm("s_add_u32 %[we], %[we], %[we]\n\t"                            \
            "s_cbranch_scc0 Lskip%=\n\t"                                   \
            "v_pk_max_i16 %[mx0], %[mx0], %[vx]\n\t"                       \
            "v_pk_max_i16 %[mx1], %[mx1], %[vy]\n\t"                       \
            "v_pk_min_u16 %[mn0], %[mn0], %[vx]\n\t"                       \
            "v_pk_min_u16 %[mn1], %[mn1], %[vy]\n"                         \
            "Lskip%=:"                                                     \
            : [we] "+s"(WE),                                               \
              [mx0] "+v"(MX0), [mx1] "+v"(MX1),                            \
              [mn0] "+v"(MN0), [mn1] "+v"(MN1)                             \
            : [vx] "v"(VX), [vy] "v"(VY)                                   \
            : "scc");                                                      \
    }

__launch_bounds__(512, 8)
__global__ void k_pool9(const unsigned short* __restrict__ hAll,
                        const unsigned* __restrict__ packed,
                        const float* __restrict__ Wscore,
                        const float* __restrict__ bscore,
                        float* __restrict__ out) {
    __shared__ __align__(16) unsigned bits[4 * 128];
    __shared__ __align__(16) unsigned part[8][4][64][4];

    const int t  = threadIdx.x;
    const int wv = t >> 6;
    const int l  = t & 63;
    const int e0 = blockIdx.x * 4;
    const int br = blockIdx.y;
    const unsigned short* h = hAll + (size_t)br * 4096 * 256;

    if (t < 128) ((uint4*)bits)[t] = ((const uint4*)(packed + e0 * 128))[t];
    __syncthreads();

    unsigned mx0[4], mx1[4], mn0[4], mn1[4];
#pragma unroll
    for (int e = 0; e < 4; e++) {
        mx0[e] = 0x80008000u; mx1[e] = 0x80008000u;
        mn0[e] = 0xFFFFFFFFu; mn1[e] = 0xFFFFFFFFu;
    }

#pragma unroll 1
    for (int ch = 0; ch < 16; ch++) {
        const int w0 = wv * 16 + ch;
        unsigned we0 = (unsigned)__builtin_amdgcn_readfirstlane((int)bits[0 * 128 + w0]);
        unsigned we1 = (unsigned)__builtin_amdgcn_readfirstlane((int)bits[1 * 128 + w0]);
        unsigned we2 = (unsigned)__builtin_amdgcn_readfirstlane((int)bits[2 * 128 + w0]);
        unsigned we3 = (unsigned)__builtin_amdgcn_readfirstlane((int)bits[3 * 128 + w0]);

        const unsigned short* hp = h + (size_t)(wv * 512 + ch * 32) * 256 + 4 * l;
#pragma unroll
        for (int jj = 0; jj < 8; jj++) {
            uint2 v0 = *(const uint2*)(hp + (jj * 4 + 0) * 256);
            uint2 v1 = *(const uint2*)(hp + (jj * 4 + 1) * 256);
            uint2 v2 = *(const uint2*)(hp + (jj * 4 + 2) * 256);
            uint2 v3 = *(const uint2*)(hp + (jj * 4 + 3) * 256);

            POOL_STEP(we0, mx0[0], mx1[0], mn0[0], mn1[0], v0.x, v0.y);
            POOL_STEP(we1, mx0[1], mx1[1], mn0[1], mn1[1], v0.x, v0.y);
            POOL_STEP(we2, mx0[2], mx1[2], mn0[2], mn1[2], v0.x, v0.y);
            POOL_STEP(we3, mx0[3], mx1[3], mn0[3], mn1[3], v0.x, v0.y);
            POOL_STEP(we0, mx0[0], mx1[0], mn0[0], mn1[0], v1.x, v1.y);
            POOL_STEP(we1, mx0[1], mx1[1], mn0[1], mn1[1], v1.x, v1.y);
            POOL_STEP(we2, mx0[2], mx1[2], mn0[2], mn1[2], v1.x, v1.y);
            POOL_STEP(we3, mx0[3], mx1[3], mn0[3], mn1[3], v1.x, v1.y);
            POOL_STEP(we0, mx0[0], mx1[0], mn0[0], mn1[0], v2.x, v2.y);
            POOL_STEP(we1, mx0[1], mx1[1], mn0[1], mn1[1], v2.x, v2.y);
            POOL_STEP(we2, mx0[2], mx1[2], mn0[2], mn1[2], v2.x, v2.y);
            POOL_STEP(we3, mx0[3], mx1[3], mn0[3], mn1[3], v2.x, v2.y);
            POOL_STEP(we0, mx0[0], mx1[0], mn0[0], mn1[0], v3.x, v3.y);
            POOL_STEP(we1, mx0[1], mx1[1], mn0[1], mn1[1], v3.x, v3.y);
            POOL_STEP(we2, mx0[2], mx1[2], mn0[2], mn1[2], v3.x, v3.y);
            POOL_STEP(we3, mx0[3], mx1[3], mn0[3], mn1[3], v3.x, v3.y);
        }
    }

#pragma unroll
    for (int e = 0; e < 4; e++) {
        uint4 p; p.x = mx0[e]; p.y = mx1[e]; p.z = mn0[e]; p.w = mn1[e];
        *(uint4*)&part[wv][e][l][0] = p;
    }
    __syncthreads();

    if (wv < 4) {
        unsigned rmx0 = 0x80008000u, rmx1 = 0x80008000u;
        unsigned rmn0 = 0xFFFFFFFFu, rmn1 = 0xFFFFFFFFu;
#pragma unroll
        for (int w2 = 0; w2 < 8; w2++) {
            uint4 p = *(const uint4*)&part[w2][wv][l][0];
            rmx0 = pkmax_i16(rmx0, p.x);  rmx1 = pkmax_i16(rmx1, p.y);
            rmn0 = pkmin_u16(rmn0, p.z);  rmn1 = pkmin_u16(rmn1, p.w);
        }
        float4 wsv = *(const float4*)(Wscore + 4 * l);
        const float bsc = *bscore;
        float s = (f16u_to_f(rmx0)       - f16u_to_f(rmn0))       * wsv.x
                + (f16u_to_f(rmx0 >> 16) - f16u_to_f(rmn0 >> 16)) * wsv.y
                + (f16u_to_f(rmx1)       - f16u_to_f(rmn1))       * wsv.z
                + (f16u_to_f(rmx1 >> 16) - f16u_to_f(rmn1 >> 16)) * wsv.w;
#pragma unroll
        for (int off = 32; off; off >>= 1) s += __shfl_xor(s, off);
        if (l == 0)
            out[br * 4096 + e0 + wv] = 1.f / (1.f + __expf(-(s + bsc)));
    }
}

// ---------------------------------------------------------------- launch
extern "C" void kernel_launch(void* const* d_in, const int* in_sizes, int n_in,
                              void* d_out, int out_size, void* d_ws, size_t ws_size,
                              hipStream_t stream) {
    const float* pf  = (const float*)d_in[0];
    const float* pm  = (const float*)d_in[1];
    const float* nf  = (const float*)d_in[2];
    const float* nm  = (const float*)d_in[3];
    const int*   msk = (const int*)d_in[4];
    const float* Wsf = (const float*)d_in[5];
    const float* bsf = (const float*)d_in[6];
    const float* Whp = (const float*)d_in[7];
    const float* bhp = (const float*)d_in[8];
    const float* Wsc = (const float*)d_in[9];
    const float* bsc = (const float*)d_in[10];
    float* out = (float*)d_out;

    char* ws = (char*)d_ws;
    const size_t MB = 1024u * 1024u;
    unsigned short* hbuf  = (unsigned short*)(ws);                     // 4 MB: hT (main) or h row-major (fallback)
    unsigned*       pck   = (unsigned*)(ws + 4 * MB);                  // 2 MB  [4096][128]
    unsigned short* Wts   = (unsigned short*)(ws + 6 * MB);            // 128 KB
    unsigned short* Wth   = Wts + 256 * 256;                           // 128 KB
    unsigned*       topkG = (unsigned*)(ws + 6 * MB + 256 * 1024);     // 128 KB [2][64][256]
    unsigned*       botkG = (unsigned*)(ws + 6 * MB + 384 * 1024);     // 128 KB [2][64][256]
    const size_t need = 6 * MB + 512 * 1024;

    k_prepW<<<dim3(4, 4, 2), 256, 0, stream>>>(Wsf, Whp, Wts, Wth);

    if (ws_size >= need) {
        k_gemm_relu<<<dim3(64, 4, 2), 256, 0, stream>>>(pf, pm, nf, nm, Wts, Wth, bsf, bhp, hbuf, 1);
        k_sortpack<<<dim3(256, 2), 512, 0, stream>>>(hbuf, msk, pck, topkG, botkG);
        k_probe<<<dim3(256, 2), 256, 0, stream>>>(topkG, botkG, pck, hbuf, Wsc, bsc, out);
    } else {
        // small-ws fallback: round-13 brute-force pool (needs only ~6.25 MB)
        k_pack<<<2048, 256, 0, stream>>>(msk, pck);
        k_gemm_relu<<<dim3(64, 4, 2), 256, 0, stream>>>(pf, pm, nf, nm, Wts, Wth, bsf, bhp, hbuf, 0);
        k_pool9<<<dim3(1024, 2), 512, 0, stream>>>(hbuf, pck, Wsc, bsc, out);
    }
}